// Round 13
// baseline (859.756 us; speedup 1.0000x reference)
//
#include <hip/hip_runtime.h>
#include <math.h>

constexpr int kH = 64, kW = 128, kB = 2, kS = 4;
constexpr int kNP = kH * kW;          // 8192 points per set
constexpr int kPairs = kB * kS;       // 8
constexpr int kDirs = kPairs * 2;     // 16
constexpr float kPen = 32768.0f;      // padding penalty (bf16-exact pow2)
constexpr float kPi = 3.14159265358979323846f;
constexpr float kFovUp = 3.0f * kPi / 180.0f;
constexpr float kFovDown = -25.0f * kPi / 180.0f;

typedef short short8 __attribute__((ext_vector_type(8)));
typedef unsigned short ushort8 __attribute__((ext_vector_type(8)));
typedef float floatx4 __attribute__((ext_vector_type(4)));

// nn tiling (R12 anchor: mfma_f32_16x16x32_bf16 + fminf folds + fence-free
// ticket tail), now on COMPACTED point sets (~50% of points valid).
constexpr int NCC = 8;                // candidate chunks of 1024
constexpr int CCH = 1024;
constexpr int NQB = 16;               // query blocks of 512
// grid = 16 dirs * 16 * 8 = 2048 blocks, 128 per dir; blocks beyond the
// valid counts early-exit to the ticket.

// ws layout (float offsets)
// cpts : [kDirs][kNP] float4 -> 524288 @ 0      (2 MB; only cnt[d] entries live)
// min  : [kDirs][kNP] u32    -> 131072 @ 524288 (0.5 MB)
// cnt  : [16] u32  @ 655360   \
// dcnt : [16] u32  @ 655376    > zeroed by one hipMemsetAsync (132 B)
// acnt : u32       @ 655392   /
// mval : [16] f32  @ 655408
constexpr size_t OFF_MIN = 524288;
constexpr size_t OFF_CNT = 655360;
constexpr size_t OFF_DCNT = 655376;
constexpr size_t OFF_ACNT = 655392;
constexpr size_t OFF_MVAL = 655408;

__device__ __forceinline__ unsigned short f2bf(float v) {
  unsigned u = __float_as_uint(v);
  unsigned r = u + 0x7FFFu + ((u >> 16) & 1u);   // RNE
  return (unsigned short)(r >> 16);
}
__device__ __forceinline__ float bf2f(unsigned short b) {
  return __uint_as_float(((unsigned)b) << 16);
}

// Candidate record F (16 bf16 slots; K-quads: q0=k0..7, q1=k8..15, q2/q3=0)
// pairs with query record G:
//  k : 0    1    2    3    4    5    6    7  | 8    9    10   11   12-15
//  F : Xh   Xl   Xh   Yh   Yl   Yh   Zh   Zl | Zh   Ch   Cl   Cl2  0
//  G : xh   xh   xl   yh   yh   yl   zh   zh | zl   1    1    1    0
// sum_k F*G = X*x + Y*y + Z*z + ct  (drops only lo*lo terms ~2e-4)

__global__ __launch_bounds__(256) void prep_kernel(
    const float* __restrict__ rv, const float* __restrict__ tgt,
    float4* __restrict__ cpts, unsigned* __restrict__ minarr,
    unsigned* __restrict__ cnt) {
  int idx = blockIdx.x * 256 + threadIdx.x;   // [0, kPairs*kNP)
  int p = idx >> 13;
  int k = idx & (kNP - 1);
  int h = k >> 7;
  int w = k & 127;

  float r = rv[idx];
  float pitch = (1.0f - (h + 0.5f) * (1.0f / kH)) * (kFovUp - kFovDown) + kFovDown;
  float yaw = -(((w + 0.5f) * (1.0f / kW)) * 2.0f - 1.0f) * kPi;
  float cp = __cosf(pitch), sp = __sinf(pitch);
  float cy = __cosf(yaw), sy = __sinf(yaw);
  float px = r * cp * cy, py = r * cp * sy, pz = r * sp;

  const float* tb = tgt + (size_t)p * 4 * kNP;
  float tx = tb[kNP + k], ty = tb[2 * kNP + k], tz = tb[3 * kNP + k];

  float no = px * px + py * py + pz * pz;
  float nt = tx * tx + ty * ty + tz * tz;

  int d0 = 2 * p, d1 = d0 + 1;
  // compact valid points; .w = |p|^2 (no penalty needed: all entries valid)
  if (r > 0.0f) {
    unsigned pos = atomicAdd(&cnt[d0], 1u);
    cpts[(size_t)d0 * kNP + pos] = make_float4(px, py, pz, no);
  }
  if (tb[k] > 0.0f) {
    unsigned pos = atomicAdd(&cnt[d1], 1u);
    cpts[(size_t)d1 * kNP + pos] = make_float4(tx, ty, tz, nt);
  }

  minarr[(size_t)d0 * kNP + k] = 0xFFFFFFFFu;
  minarr[(size_t)d1 * kNP + k] = 0xFFFFFFFFu;
}

__global__ __launch_bounds__(256, 4) void nn_kernel(
    const float4* __restrict__ cpts, unsigned* __restrict__ minarr,
    const unsigned* __restrict__ cnt, float* __restrict__ mval,
    unsigned* __restrict__ dcnt, unsigned* __restrict__ acnt,
    float* __restrict__ out) {
  // 32 KB candidate records (64 tiles of [16 x lo8][16 x hi8]) + 32 B zero tile
  __shared__ __align__(16) unsigned short sc[CCH * 16 + 16];
  __shared__ unsigned s_ticket;
  __shared__ float sw[4], sm[4];

  int bid = blockIdx.x;
  int d = bid >> 7;            // 128 blocks per dir
  int qb = (bid >> 3) & 15;
  int ch = bid & 7;
  int t = threadIdx.x;

  int cntq = (int)cnt[d];       // valid queries of this dir
  int cntc = (int)cnt[d ^ 1];   // valid candidates = partner dir's points
  int cbase = ch * 1024;
  bool active = (qb * 512 < cntq) && (cbase < cntc);

  if (active) {
    // ---- build candidate records in LDS from compacted partner points ----
    const float4* cand = cpts + (size_t)(d ^ 1) * kNP + cbase;
#pragma unroll
    for (int i = 0; i < 4; ++i) {
      int j = t + i * 256;
      float4 P = (cbase + j < cntc) ? cand[j]
                                    : make_float4(0.f, 0.f, 0.f, kPen);
      float X = -2.0f * P.x, Y = -2.0f * P.y, Z = -2.0f * P.z;
      float ct = P.w;
      unsigned short Xh = f2bf(X), Yh = f2bf(Y), Zh = f2bf(Z);
      unsigned short Xl = f2bf(X - bf2f(Xh));
      unsigned short Yl = f2bf(Y - bf2f(Yh));
      unsigned short Zl = f2bf(Z - bf2f(Zh));
      unsigned short Ch = f2bf(ct);
      float c1 = ct - bf2f(Ch);
      unsigned short Cl = f2bf(c1);
      unsigned short Cl2 = f2bf(c1 - bf2f(Cl));
      unsigned short* dst = sc + (j >> 4) * 256 + (j & 15) * 8;
      *(ushort8*)dst = (ushort8){Xh, Xl, Xh, Yh, Yl, Yh, Zh, Zl};
      *(ushort8*)(dst + 128) = (ushort8){Zh, Ch, Cl, Cl2, 0, 0, 0, 0};
    }
    if (t < 2) ((float4*)(sc + CCH * 16))[t] = make_float4(0.f, 0.f, 0.f, 0.f);
    __syncthreads();

    int wave = t >> 6, lane = t & 63;
    int n = lane & 15, q = lane >> 4;    // q = K-quad (HW-verified layout)
    int qbase = d * kNP + qb * 512 + wave * 128;

    const short one_bf = (short)0x3F80;  // bf16(1.0)
    short8 bfr[8];
    float mn[8];
#pragma unroll
    for (int i = 0; i < 8; ++i) {
      short8 b = (short8){0, 0, 0, 0, 0, 0, 0, 0};
      if (q < 2) {
        // reads past cntq hit 0xAA-poison floats (~-7.7e-13) — harmless,
        // their minarr slots are never read by the reducer.
        float4 P = cpts[qbase + i * 16 + n];
        unsigned short xh = f2bf(P.x), yh = f2bf(P.y), zh = f2bf(P.z);
        unsigned short xl = f2bf(P.x - bf2f(xh));
        unsigned short yl = f2bf(P.y - bf2f(yh));
        unsigned short zl = f2bf(P.z - bf2f(zh));
        if (q == 0)
          b = (short8){(short)xh, (short)xh, (short)xl, (short)yh,
                       (short)yh, (short)yl, (short)zh, (short)zh};
        else
          b = (short8){(short)zl, one_bf, one_bf, one_bf, 0, 0, 0, 0};
      }
      bfr[i] = b;
      mn[i] = 3.0e38f;
    }

    floatx4 zc = {0.0f, 0.0f, 0.0f, 0.0f};
    const unsigned short* aptr =
        (q < 2) ? (sc + q * 128 + n * 8) : (sc + CCH * 16);
    int astep = (q < 2) ? 256 : 0;

    int nct = (cntc - cbase + 15) >> 4;
    if (nct > 64) nct = 64;
#pragma unroll 2
    for (int ctile = 0; ctile < nct; ++ctile) {
      short8 a = *(const short8*)aptr;
      aptr += astep;
#pragma unroll
      for (int i = 0; i < 8; ++i) {
        floatx4 dr = __builtin_amdgcn_mfma_f32_16x16x32_bf16(a, bfr[i], zc, 0, 0, 0);
        float u = fminf(fminf(dr[0], dr[1]), dr[2]);
        mn[i] = fminf(fminf(u, dr[3]), mn[i]);
      }
    }

#pragma unroll
    for (int i = 0; i < 8; ++i) {
      float m = mn[i];
      m = fminf(m, __shfl_xor(m, 16));
      m = fminf(m, __shfl_xor(m, 32));
      if (lane < 16) {
        unsigned bb = __float_as_uint(m);
        unsigned e = (bb & 0x80000000u) ? ~bb : (bb | 0x80000000u);
        atomicMin(&minarr[qbase + i * 16 + lane], e);
      }
    }
  }

  // ---- ticket: last block of this dir reduces (fence-free, R12-proven) ----
  __syncthreads();
  if (t == 0)
    s_ticket = __hip_atomic_fetch_add(&dcnt[d], 1u, __ATOMIC_RELAXED,
                                      __HIP_MEMORY_SCOPE_AGENT);
  __syncthreads();
  if (s_ticket != 127u) return;

  float wsum = 0.0f;
#pragma unroll 4
  for (int j = 0; j < 32; ++j) {
    int k = j * 256 + t;
    if (k < cntq) {
      unsigned u = __hip_atomic_load(&minarr[(size_t)d * kNP + k],
                                     __ATOMIC_RELAXED, __HIP_MEMORY_SCOPE_AGENT);
      unsigned bb = (u & 0x80000000u) ? (u ^ 0x80000000u) : ~u;
      wsum += cpts[(size_t)d * kNP + k].w + __uint_as_float(bb);
    }
  }
#pragma unroll
  for (int off = 32; off; off >>= 1) wsum += __shfl_down(wsum, off);
  if ((t & 63) == 0) sw[t >> 6] = wsum;
  __syncthreads();
  if (t == 0) {
    float ws_ = sw[0] + sw[1] + sw[2] + sw[3];
    __hip_atomic_store(&mval[d], ws_ / fmaxf((float)cntq, 1.0f),
                       __ATOMIC_RELAXED, __HIP_MEMORY_SCOPE_AGENT);
    s_ticket = __hip_atomic_fetch_add(acnt, 1u, __ATOMIC_ACQ_REL,
                                      __HIP_MEMORY_SCOPE_AGENT);
  }
  __syncthreads();
  if (s_ticket != (unsigned)(kDirs - 1)) return;
  // ---- very last block combines 16 dir values into the 12 outputs ----
  if (t == 0) {
    float mv[kDirs];
    for (int dd = 0; dd < kDirs; ++dd)
      mv[dd] = __hip_atomic_load(&mval[dd], __ATOMIC_RELAXED,
                                 __HIP_MEMORY_SCOPE_AGENT);
    for (int s = 0; s < kS; ++s) {
      float acc = 0.0f;
      for (int b = 0; b < kB; ++b) {
        int p = b * kS + s;
        float tens = mv[2 * p] + mv[2 * p + 1];
        out[kS + s * kB + b] = tens;
        acc += tens;
      }
      out[s] = acc * (1.0f / kB);
    }
  }
}

extern "C" void kernel_launch(void* const* d_in, const int* in_sizes, int n_in,
                              void* d_out, int out_size, void* d_ws, size_t ws_size,
                              hipStream_t stream) {
  const float* rv = (const float*)d_in[0];
  const float* tgt = (const float*)d_in[1];
  float* ws = (float*)d_ws;
  float4* cpts = (float4*)ws;
  unsigned* minarr = (unsigned*)(ws + OFF_MIN);
  unsigned* cnt = (unsigned*)(ws + OFF_CNT);
  unsigned* dcnt = (unsigned*)(ws + OFF_DCNT);
  unsigned* acnt = (unsigned*)(ws + OFF_ACNT);
  float* mval = ws + OFF_MVAL;
  float* out = (float*)d_out;

  // zero cnt[16] + dcnt[16] + acnt (contiguous 33 words)
  hipMemsetAsync((void*)cnt, 0, 33 * sizeof(unsigned), stream);
  hipLaunchKernelGGL(prep_kernel, dim3(kPairs * kNP / 256), dim3(256), 0, stream,
                     rv, tgt, cpts, minarr, cnt);
  hipLaunchKernelGGL(nn_kernel, dim3(kDirs * NQB * NCC), dim3(256), 0, stream,
                     cpts, minarr, cnt, mval, dcnt, acnt, out);
}

// Round 14
// 136.609 us; speedup vs baseline: 6.2935x; 6.2935x over previous
//
#include <hip/hip_runtime.h>
#include <math.h>

constexpr int kH = 64, kW = 128, kB = 2, kS = 4;
constexpr int kNP = kH * kW;          // 8192 points per set
constexpr int kPairs = kB * kS;       // 8
constexpr int kDirs = kPairs * 2;     // 16
constexpr float kPen = 32768.0f;      // padding penalty (bf16-exact pow2)
constexpr float kPi = 3.14159265358979323846f;
constexpr float kFovUp = 3.0f * kPi / 180.0f;
constexpr float kFovDown = -25.0f * kPi / 180.0f;

typedef short short8 __attribute__((ext_vector_type(8)));
typedef unsigned short ushort8 __attribute__((ext_vector_type(8)));
typedef float floatx4 __attribute__((ext_vector_type(4)));

// nn tiling (R12 anchor: mfma_f32_16x16x32_bf16 + fminf folds + fence-free
// ticket tail) on COMPACTED point sets (~50% of points valid).
constexpr int NCC = 8;                // candidate chunks of 1024
constexpr int CCH = 1024;
constexpr int NQB = 16;               // query blocks of 512
// grid = 16 dirs * 16 * 8 = 2048 blocks, 128 per dir; blocks beyond the
// valid counts early-exit to the ticket.

// ws layout (float offsets)
// cpts : [kDirs][kNP] float4 -> 524288 @ 0      (2 MB; only cnt[d] entries live)
// min  : [kDirs][kNP] u32    -> 131072 @ 524288 (0.5 MB)
// cnt  : [16] u32  @ 655360   \
// dcnt : [16] u32  @ 655376    > zeroed by one hipMemsetAsync (132 B)
// acnt : u32       @ 655392   /
// mval : [16] f32  @ 655408
constexpr size_t OFF_MIN = 524288;
constexpr size_t OFF_CNT = 655360;
constexpr size_t OFF_DCNT = 655376;
constexpr size_t OFF_ACNT = 655392;
constexpr size_t OFF_MVAL = 655408;

__device__ __forceinline__ unsigned short f2bf(float v) {
  unsigned u = __float_as_uint(v);
  unsigned r = u + 0x7FFFu + ((u >> 16) & 1u);   // RNE
  return (unsigned short)(r >> 16);
}
__device__ __forceinline__ float bf2f(unsigned short b) {
  return __uint_as_float(((unsigned)b) << 16);
}

// Candidate record F (16 bf16 slots; K-quads: q0=k0..7, q1=k8..15, q2/q3=0)
// pairs with query record G:
//  k : 0    1    2    3    4    5    6    7  | 8    9    10   11   12-15
//  F : Xh   Xl   Xh   Yh   Yl   Yh   Zh   Zl | Zh   Ch   Cl   Cl2  0
//  G : xh   xh   xl   yh   yh   yl   zh   zh | zl   1    1    1    0
// sum_k F*G = X*x + Y*y + Z*z + ct  (drops only lo*lo terms ~2e-4)

__global__ __launch_bounds__(256) void prep_kernel(
    const float* __restrict__ rv, const float* __restrict__ tgt,
    float4* __restrict__ cpts, unsigned* __restrict__ minarr,
    unsigned* __restrict__ cnt) {
  int idx = blockIdx.x * 256 + threadIdx.x;   // [0, kPairs*kNP)
  int p = idx >> 13;                          // block-uniform (8192 per pair)
  int k = idx & (kNP - 1);
  int h = k >> 7;
  int w = k & 127;
  int lane = threadIdx.x & 63;

  float r = rv[idx];
  float pitch = (1.0f - (h + 0.5f) * (1.0f / kH)) * (kFovUp - kFovDown) + kFovDown;
  float yaw = -(((w + 0.5f) * (1.0f / kW)) * 2.0f - 1.0f) * kPi;
  float cp = __cosf(pitch), sp = __sinf(pitch);
  float cy = __cosf(yaw), sy = __sinf(yaw);
  float px = r * cp * cy, py = r * cp * sy, pz = r * sp;

  const float* tb = tgt + (size_t)p * 4 * kNP;
  float tv = tb[k];
  float tx = tb[kNP + k], ty = tb[2 * kNP + k], tz = tb[3 * kNP + k];

  float no = px * px + py * py + pz * pz;
  float nt = tx * tx + ty * ty + tz * tz;

  int d0 = 2 * p, d1 = d0 + 1;
  unsigned long long lt = (1ull << lane) - 1ull;

  // ---- wave-compacted append: ONE atomicAdd per wave per counter ----
  // (R13 post-mortem: per-lane atomicAdd with used return value cannot be
  //  wave-coalesced -> 65536 serialized RMWs -> 745 us. This is the fix.)
  {
    bool v = (r > 0.0f);
    unsigned long long m = __ballot(v);
    int total = __popcll(m);
    int prefix = __popcll(m & lt);
    unsigned base = 0;
    if (lane == 0 && total) base = atomicAdd(&cnt[d0], (unsigned)total);
    base = (unsigned)__shfl((int)base, 0);
    if (v) cpts[(size_t)d0 * kNP + base + prefix] = make_float4(px, py, pz, no);
  }
  {
    bool v = (tv > 0.0f);
    unsigned long long m = __ballot(v);
    int total = __popcll(m);
    int prefix = __popcll(m & lt);
    unsigned base = 0;
    if (lane == 0 && total) base = atomicAdd(&cnt[d1], (unsigned)total);
    base = (unsigned)__shfl((int)base, 0);
    if (v) cpts[(size_t)d1 * kNP + base + prefix] = make_float4(tx, ty, tz, nt);
  }

  minarr[(size_t)d0 * kNP + k] = 0xFFFFFFFFu;
  minarr[(size_t)d1 * kNP + k] = 0xFFFFFFFFu;
}

__global__ __launch_bounds__(256, 4) void nn_kernel(
    const float4* __restrict__ cpts, unsigned* __restrict__ minarr,
    const unsigned* __restrict__ cnt, float* __restrict__ mval,
    unsigned* __restrict__ dcnt, unsigned* __restrict__ acnt,
    float* __restrict__ out) {
  // 32 KB candidate records (64 tiles of [16 x lo8][16 x hi8]) + 32 B zero tile
  __shared__ __align__(16) unsigned short sc[CCH * 16 + 16];
  __shared__ unsigned s_ticket;
  __shared__ float sw[4];

  int bid = blockIdx.x;
  int d = bid >> 7;            // 128 blocks per dir
  int qb = (bid >> 3) & 15;
  int ch = bid & 7;
  int t = threadIdx.x;

  int cntq = (int)cnt[d];       // valid queries of this dir
  int cntc = (int)cnt[d ^ 1];   // valid candidates = partner dir's points
  int cbase = ch * 1024;
  bool active = (qb * 512 < cntq) && (cbase < cntc);

  if (active) {
    // ---- build candidate records in LDS from compacted partner points ----
    const float4* cand = cpts + (size_t)(d ^ 1) * kNP + cbase;
#pragma unroll
    for (int i = 0; i < 4; ++i) {
      int j = t + i * 256;
      float4 P = (cbase + j < cntc) ? cand[j]
                                    : make_float4(0.f, 0.f, 0.f, kPen);
      float X = -2.0f * P.x, Y = -2.0f * P.y, Z = -2.0f * P.z;
      float ct = P.w;
      unsigned short Xh = f2bf(X), Yh = f2bf(Y), Zh = f2bf(Z);
      unsigned short Xl = f2bf(X - bf2f(Xh));
      unsigned short Yl = f2bf(Y - bf2f(Yh));
      unsigned short Zl = f2bf(Z - bf2f(Zh));
      unsigned short Ch = f2bf(ct);
      float c1 = ct - bf2f(Ch);
      unsigned short Cl = f2bf(c1);
      unsigned short Cl2 = f2bf(c1 - bf2f(Cl));
      unsigned short* dst = sc + (j >> 4) * 256 + (j & 15) * 8;
      *(ushort8*)dst = (ushort8){Xh, Xl, Xh, Yh, Yl, Yh, Zh, Zl};
      *(ushort8*)(dst + 128) = (ushort8){Zh, Ch, Cl, Cl2, 0, 0, 0, 0};
    }
    if (t < 2) ((float4*)(sc + CCH * 16))[t] = make_float4(0.f, 0.f, 0.f, 0.f);
    __syncthreads();

    int wave = t >> 6, lane = t & 63;
    int n = lane & 15, q = lane >> 4;    // q = K-quad (HW-verified layout)
    int qbase = d * kNP + qb * 512 + wave * 128;

    const short one_bf = (short)0x3F80;  // bf16(1.0)
    short8 bfr[8];
    float mn[8];
#pragma unroll
    for (int i = 0; i < 8; ++i) {
      short8 b = (short8){0, 0, 0, 0, 0, 0, 0, 0};
      if (q < 2) {
        // reads past cntq hit stale/poison floats — harmless, their minarr
        // slots are never read by the reducer.
        float4 P = cpts[qbase + i * 16 + n];
        unsigned short xh = f2bf(P.x), yh = f2bf(P.y), zh = f2bf(P.z);
        unsigned short xl = f2bf(P.x - bf2f(xh));
        unsigned short yl = f2bf(P.y - bf2f(yh));
        unsigned short zl = f2bf(P.z - bf2f(zh));
        if (q == 0)
          b = (short8){(short)xh, (short)xh, (short)xl, (short)yh,
                       (short)yh, (short)yl, (short)zh, (short)zh};
        else
          b = (short8){(short)zl, one_bf, one_bf, one_bf, 0, 0, 0, 0};
      }
      bfr[i] = b;
      mn[i] = 3.0e38f;
    }

    floatx4 zc = {0.0f, 0.0f, 0.0f, 0.0f};
    const unsigned short* aptr =
        (q < 2) ? (sc + q * 128 + n * 8) : (sc + CCH * 16);
    int astep = (q < 2) ? 256 : 0;

    int nct = (cntc - cbase + 15) >> 4;
    if (nct > 64) nct = 64;
#pragma unroll 2
    for (int ctile = 0; ctile < nct; ++ctile) {
      short8 a = *(const short8*)aptr;
      aptr += astep;
#pragma unroll
      for (int i = 0; i < 8; ++i) {
        floatx4 dr = __builtin_amdgcn_mfma_f32_16x16x32_bf16(a, bfr[i], zc, 0, 0, 0);
        float u = fminf(fminf(dr[0], dr[1]), dr[2]);
        mn[i] = fminf(fminf(u, dr[3]), mn[i]);
      }
    }

#pragma unroll
    for (int i = 0; i < 8; ++i) {
      float m = mn[i];
      m = fminf(m, __shfl_xor(m, 16));
      m = fminf(m, __shfl_xor(m, 32));
      if (lane < 16) {
        unsigned bb = __float_as_uint(m);
        unsigned e = (bb & 0x80000000u) ? ~bb : (bb | 0x80000000u);
        atomicMin(&minarr[qbase + i * 16 + lane], e);
      }
    }
  }

  // ---- ticket: last block of this dir reduces (fence-free, R12-proven) ----
  __syncthreads();
  if (t == 0)
    s_ticket = __hip_atomic_fetch_add(&dcnt[d], 1u, __ATOMIC_RELAXED,
                                      __HIP_MEMORY_SCOPE_AGENT);
  __syncthreads();
  if (s_ticket != 127u) return;

  float wsum = 0.0f;
#pragma unroll 4
  for (int j = 0; j < 32; ++j) {
    int k = j * 256 + t;
    if (k < cntq) {
      unsigned u = __hip_atomic_load(&minarr[(size_t)d * kNP + k],
                                     __ATOMIC_RELAXED, __HIP_MEMORY_SCOPE_AGENT);
      unsigned bb = (u & 0x80000000u) ? (u ^ 0x80000000u) : ~u;
      wsum += cpts[(size_t)d * kNP + k].w + __uint_as_float(bb);
    }
  }
#pragma unroll
  for (int off = 32; off; off >>= 1) wsum += __shfl_down(wsum, off);
  if ((t & 63) == 0) sw[t >> 6] = wsum;
  __syncthreads();
  if (t == 0) {
    float ws_ = sw[0] + sw[1] + sw[2] + sw[3];
    __hip_atomic_store(&mval[d], ws_ / fmaxf((float)cntq, 1.0f),
                       __ATOMIC_RELAXED, __HIP_MEMORY_SCOPE_AGENT);
    s_ticket = __hip_atomic_fetch_add(acnt, 1u, __ATOMIC_ACQ_REL,
                                      __HIP_MEMORY_SCOPE_AGENT);
  }
  __syncthreads();
  if (s_ticket != (unsigned)(kDirs - 1)) return;
  // ---- very last block combines 16 dir values into the 12 outputs ----
  if (t == 0) {
    float mv[kDirs];
    for (int dd = 0; dd < kDirs; ++dd)
      mv[dd] = __hip_atomic_load(&mval[dd], __ATOMIC_RELAXED,
                                 __HIP_MEMORY_SCOPE_AGENT);
    for (int s = 0; s < kS; ++s) {
      float acc = 0.0f;
      for (int b = 0; b < kB; ++b) {
        int p = b * kS + s;
        float tens = mv[2 * p] + mv[2 * p + 1];
        out[kS + s * kB + b] = tens;
        acc += tens;
      }
      out[s] = acc * (1.0f / kB);
    }
  }
}

extern "C" void kernel_launch(void* const* d_in, const int* in_sizes, int n_in,
                              void* d_out, int out_size, void* d_ws, size_t ws_size,
                              hipStream_t stream) {
  const float* rv = (const float*)d_in[0];
  const float* tgt = (const float*)d_in[1];
  float* ws = (float*)d_ws;
  float4* cpts = (float4*)ws;
  unsigned* minarr = (unsigned*)(ws + OFF_MIN);
  unsigned* cnt = (unsigned*)(ws + OFF_CNT);
  unsigned* dcnt = (unsigned*)(ws + OFF_DCNT);
  unsigned* acnt = (unsigned*)(ws + OFF_ACNT);
  float* mval = ws + OFF_MVAL;
  float* out = (float*)d_out;

  // zero cnt[16] + dcnt[16] + acnt (contiguous 33 words)
  hipMemsetAsync((void*)cnt, 0, 33 * sizeof(unsigned), stream);
  hipLaunchKernelGGL(prep_kernel, dim3(kPairs * kNP / 256), dim3(256), 0, stream,
                     rv, tgt, cpts, minarr, cnt);
  hipLaunchKernelGGL(nn_kernel, dim3(kDirs * NQB * NCC), dim3(256), 0, stream,
                     cpts, minarr, cnt, mval, dcnt, acnt, out);
}